// Round 14
// baseline (1131.974 us; speedup 1.0000x reference)
//
#include <hip/hip_runtime.h>
#include <hip/hip_bf16.h>
#include <stdint.h>

#define DEVI static __device__ __forceinline__

typedef __bf16 bf16x8 __attribute__((ext_vector_type(8)));
typedef float f32x4 __attribute__((ext_vector_type(4)));
typedef int   int4v __attribute__((ext_vector_type(4)));
typedef int   int2v __attribute__((ext_vector_type(2)));

DEVI float bf2f(uint16_t u){ uint32_t x = ((uint32_t)u) << 16; float f; __builtin_memcpy(&f, &x, 4); return f; }
DEVI uint16_t f2bf(float f){ uint32_t u; __builtin_memcpy(&u, &f, 4); uint32_t r = (u + 0x7FFFu + ((u >> 16) & 1u)) >> 16; return (uint16_t)r; }
DEVI float frcp(float x){ return __builtin_amdgcn_rcpf(x); }
DEVI float sigm(float x){ return frcp(1.f + __expf(-x)); }
DEVI float tanhfast(float x){ return 1.f - 2.f * frcp(1.f + __expf(2.f * x)); }
DEVI f32x4 mfma16(bf16x8 a, bf16x8 b, f32x4 c){ return __builtin_amdgcn_mfma_f32_16x16x32_bf16(a, b, c, 0, 0, 0); }

DEVI bf16x8 cvt8(const float* __restrict__ p){
    f32x4 a = *(const f32x4*)p, b = *(const f32x4*)(p + 4);
    union { bf16x8 v; uint16_t u[8]; } r;
    #pragma unroll
    for (int e = 0; e < 4; ++e) { r.u[e] = f2bf(a[e]); r.u[4 + e] = f2bf(b[e]); }
    return r.v;
}
DEVI int4v asint4(bf16x8 v){ int4v r; __builtin_memcpy(&r, &v, 16); return r; }

// raw barrier: lgkm drain only (vm ops — prefetch loads / Y stores — stay in flight)
DEVI void bar_lds(){
    asm volatile("s_waitcnt lgkmcnt(0)" ::: "memory");
    __builtin_amdgcn_s_barrier();
    __builtin_amdgcn_sched_barrier(0);
}

// XG layout (row-major, t-major rows): element (t, b, c) at (t*512 + b)*768 + c.
// XG cols 0..511 (r,z gates) have bhh folded in; cols 512..767 (n gate) do NOT.

// ---------------------------------------------------------------------------
// Kernel 1: input projection (B*L,64)@(64,256) + bias + ReLU + LN -> Y bf16
// ---------------------------------------------------------------------------
__global__ __launch_bounds__(256) void k_inproj(
    const float* __restrict__ X, const float* __restrict__ W,
    const float* __restrict__ bias, const float* __restrict__ g,
    const float* __restrict__ beta, uint16_t* __restrict__ Y)
{
    __shared__ __align__(16) char As[64 * 128];
    __shared__ __align__(16) char Bs[256 * 128];
    __shared__ __align__(16) char Cs[64 * 520];
    const int tid = threadIdx.x;
    const long rowbase = (long)blockIdx.x * 64;

    #pragma unroll
    for (int it = 0; it < 2; ++it) {
        int c = it * 256 + tid; int r = c >> 3, cc = c & 7;
        bf16x8 v = cvt8(X + (rowbase + r) * 64 + cc * 8);
        *(int4v*)(As + r * 128 + ((cc * 16) ^ ((r & 7) << 4))) = asint4(v);
    }
    #pragma unroll
    for (int it = 0; it < 8; ++it) {
        int c = it * 256 + tid; int r = c >> 3, cc = c & 7;
        bf16x8 v = cvt8(W + r * 64 + cc * 8);
        *(int4v*)(Bs + r * 128 + ((cc * 16) ^ ((r & 7) << 4))) = asint4(v);
    }
    __syncthreads();

    const int w = tid >> 6, l = tid & 63, lr = l & 15, lg = l >> 4;
    f32x4 acc[16];
    #pragma unroll
    for (int i = 0; i < 16; ++i) acc[i] = (f32x4){0.f, 0.f, 0.f, 0.f};
    const int arow = w * 16 + lr;
    #pragma unroll
    for (int ks = 0; ks < 2; ++ks) {
        bf16x8 a = *(bf16x8*)(As + arow * 128 + ((ks * 64 + lg * 16) ^ ((arow & 7) << 4)));
        #pragma unroll
        for (int tl = 0; tl < 16; ++tl) {
            int n = tl * 16 + lr;
            bf16x8 b = *(bf16x8*)(Bs + n * 128 + ((ks * 64 + lg * 16) ^ ((n & 7) << 4)));
            acc[tl] = mfma16(a, b, acc[tl]);
        }
    }
    float gv[16], bv[16], biasv[16];
    #pragma unroll
    for (int tl = 0; tl < 16; ++tl) {
        int col = tl * 16 + lr;
        gv[tl] = g[col]; bv[tl] = beta[col]; biasv[tl] = bias[col];
    }
    #pragma unroll
    for (int i = 0; i < 4; ++i) {
        float s = 0.f, sq = 0.f, v[16];
        #pragma unroll
        for (int tl = 0; tl < 16; ++tl) {
            float xv = acc[tl][i] + biasv[tl]; xv = fmaxf(xv, 0.f);
            v[tl] = xv; s += xv; sq += xv * xv;
        }
        #pragma unroll
        for (int d = 1; d < 16; d <<= 1) { s += __shfl_xor(s, d); sq += __shfl_xor(sq, d); }
        float mean = s * (1.f / 256.f);
        float var  = sq * (1.f / 256.f) - mean * mean;
        float sc   = rsqrtf(var + 1e-5f);
        int rl = w * 16 + lg * 4 + i;
        #pragma unroll
        for (int tl = 0; tl < 16; ++tl)
            *(uint16_t*)(Cs + rl * 520 + (tl * 16 + lr) * 2) =
                f2bf((v[tl] - mean) * sc * gv[tl] + bv[tl]);
    }
    __syncthreads();
    #pragma unroll
    for (int it = 0; it < 16; ++it) {
        int idx = it * 256 + tid;
        int rl = idx >> 6, ch = idx & 63;
        long rg = rowbase + rl;
        long ri = ((rg & 127) << 9) + (rg >> 7);      // t-major
        *(int2v*)(Y + ri * 256 + ch * 4) = *(int2v*)(Cs + rl * 520 + ch * 8);
    }
}

// ---------------------------------------------------------------------------
// Kernel 2: input-gate GEMM. bhh folded into bias for cols < 512 (r,z gates).
// grid (64, 4) x 512 thr.
// ---------------------------------------------------------------------------
template<int KIN, bool ZBUILD>
__global__ __launch_bounds__(512) void k_xg(
    const uint16_t* __restrict__ A, const float* __restrict__ W,
    const float* __restrict__ bias, const float* __restrict__ bhh,
    uint16_t* __restrict__ XG,
    const float* __restrict__ zbuf, const float* __restrict__ noise)
{
    constexpr int KB = KIN * 2;
    constexpr int KS = KIN / 32;
    __shared__ __align__(16) char Bs[192 * KB];
    __shared__ __align__(16) char Cs[128 * 400];
    const int tid = threadIdx.x;
    const int nb = blockIdx.y;

    constexpr int CPR = KIN / 8;
    for (int c = tid; c < 192 * CPR; c += 512) {
        int r = c / CPR, cc = c % CPR;
        bf16x8 v = cvt8(W + (long)(nb * 192 + r) * KIN + cc * 8);
        *(int4v*)(Bs + r * KB + ((cc * 16) ^ ((r & 7) << 4))) = asint4(v);
    }
    __syncthreads();

    const int w = tid >> 6, l = tid & 63, lr = l & 15, lg = l >> 4;
    float bvs[12];
    #pragma unroll
    for (int tl = 0; tl < 12; ++tl) {
        int colg = nb * 192 + tl * 16 + lr;
        bvs[tl] = bias[colg] + (colg < 512 ? bhh[colg] : 0.f);
    }

    for (int rt = 0; rt < 8; ++rt) {
        const long rowb = (long)blockIdx.x * 1024 + rt * 128;
        const long ria  = rowb + w * 16 + lr;
        bf16x8 a[KS];
        if constexpr (!ZBUILD) {
            #pragma unroll
            for (int ks = 0; ks < KS; ++ks)
                a[ks] = *(const bf16x8*)(A + ria * KIN + ks * 32 + lg * 8);
        } else {
            int b = (int)(ria & 511), t = (int)(ria >> 9);
            #pragma unroll
            for (int ks = 0; ks < KS; ++ks) {
                int k0 = ks * 32 + lg * 8;
                const float* zr = zbuf + b * 64 + k0;
                const float* nr = noise + ((long)b * 128 + t) * 64 + k0;
                f32x4 z0 = *(const f32x4*)zr, z1 = *(const f32x4*)(zr + 4);
                f32x4 n0 = *(const f32x4*)nr, n1 = *(const f32x4*)(nr + 4);
                union { bf16x8 v; uint16_t u[8]; } un;
                #pragma unroll
                for (int e = 0; e < 4; ++e) {
                    un.u[e]     = f2bf(z0[e] + 0.05f * n0[e]);
                    un.u[4 + e] = f2bf(z1[e] + 0.05f * n1[e]);
                }
                a[ks] = un.v;
            }
        }
        f32x4 acc[12];
        #pragma unroll
        for (int i = 0; i < 12; ++i) acc[i] = (f32x4){0.f, 0.f, 0.f, 0.f};
        #pragma unroll
        for (int ks = 0; ks < KS; ++ks) {
            #pragma unroll
            for (int tl = 0; tl < 12; ++tl) {
                int n = tl * 16 + lr;
                bf16x8 b = *(bf16x8*)(Bs + n * KB + ((ks * 64 + lg * 16) ^ ((n & 7) << 4)));
                acc[tl] = mfma16(a[ks], b, acc[tl]);
            }
        }
        #pragma unroll
        for (int tl = 0; tl < 12; ++tl) {
            #pragma unroll
            for (int i = 0; i < 4; ++i)
                *(uint16_t*)(Cs + (w * 16 + lg * 4 + i) * 400 + (tl * 16 + lr) * 2) =
                    f2bf(acc[tl][i] + bvs[tl]);
        }
        __syncthreads();
        #pragma unroll
        for (int it = 0; it < 6; ++it) {
            int idx = it * 512 + tid;
            int row = idx / 24, ch = idx % 24;
            *(int4v*)(XG + (rowb + row) * 768 + nb * 192 + ch * 8) =
                *(int4v*)(Cs + row * 400 + ch * 16);
        }
        __syncthreads();
    }
}

// ---------------------------------------------------------------------------
// Kernel 3a: persistent GRU, 4-wave variant (encoder layers). 256 thr.
// ALL of Whh register-resident: wf[12][8] (384 regs; 1 wave/SIMD budget 512).
// LDS only holds h (2KB): 8 A-reads/wave/step, no Wt. Per-lane gate work = 2
// outputs (static SEL cndmasks). bhh r/z folded into XG; bN kept.
// ---------------------------------------------------------------------------
__global__ __launch_bounds__(256)
__attribute__((amdgpu_waves_per_eu(1, 1)))
void k_gru4(
    const uint16_t* __restrict__ XG, const float* __restrict__ Whh,
    const float* __restrict__ bhh, uint16_t* __restrict__ Y,
    float* __restrict__ hlast)
{
    constexpr int L = 128;
    __shared__ __align__(16) char Abuf[2][2 * 512];
    const int tid = threadIdx.x;
    const int w = tid >> 6, l = tid & 63, lr = l & 15, lg = l >> 4;
    const int rowg0 = blockIdx.x * 2;

    ((uint32_t*)Abuf)[tid] = 0;
    ((uint32_t*)Abuf)[256 + tid] = 0;

    int gb[12];
    #pragma unroll
    for (int tl = 0; tl < 12; ++tl) gb[tl] = (tl >> 2) * 256 + w * 64 + (tl & 3) * 16;
    bf16x8 wf[12][8];
    #pragma unroll
    for (int tl = 0; tl < 12; ++tl)
        #pragma unroll
        for (int ks = 0; ks < 8; ++ks)
            wf[tl][ks] = cvt8(Whh + (long)(gb[tl] + lr) * 256 + ks * 32 + lg * 8);

    const int row = lg & 1;
    const int hi  = (lg >> 1) & 1;                    // col-group pair select
    const int col0 = w * 64 + hi * 32 + lr;           // e=0: cg = hi*2
    const int col1 = col0 + 16;                       // e=1: cg = hi*2+1
    const long rowl = rowg0 + row;
    const float bN0 = bhh[512 + col0], bN1 = bhh[512 + col1];
    const int wr0 = row * 512 + ((((col0 * 2) & ~15) ^ (row << 6)) | ((col0 * 2) & 15));
    const int wr1 = row * 512 + ((((col1 * 2) & ~15) ^ (row << 6)) | ((col1 * 2) & 15));

    uint16_t xr0 = XG[rowl * 768 + col0], xz0 = XG[rowl * 768 + 256 + col0], xn0 = XG[rowl * 768 + 512 + col0];
    uint16_t xr1 = XG[rowl * 768 + col1], xz1 = XG[rowl * 768 + 256 + col1], xn1 = XG[rowl * 768 + 512 + col1];
    float h0 = 0.f, h1 = 0.f;
    const bool wy = (Y != nullptr);
    const int arow = lr & 1;
    __syncthreads();

    for (int t = 0; t < L; ++t) {
        const int p = t & 1;
        const char* ab = Abuf[p];
        f32x4 acc[12];
        #pragma unroll
        for (int i = 0; i < 12; ++i) acc[i] = (f32x4){0.f, 0.f, 0.f, 0.f};
        #pragma unroll
        for (int ks = 0; ks < 8; ++ks) {
            bf16x8 a = *(bf16x8*)(ab + arow * 512 + ((ks * 64 + lg * 16) ^ (arow << 6)));
            #pragma unroll
            for (int tl = 0; tl < 12; ++tl) acc[tl] = mfma16(a, wf[tl][ks], acc[tl]);
        }

        // pre-activation select: acc[g*4 + (hi?2:0) + e][row]  (static indices)
        #define SELG(tA, tB) (hi ? (row ? acc[tB][1] : acc[tB][0]) \
                                 : (row ? acc[tA][1] : acc[tA][0]))
        float pR0 = SELG(0, 2),  pR1 = SELG(1, 3);
        float pZ0 = SELG(4, 6),  pZ1 = SELG(5, 7);
        float pN0 = SELG(8, 10), pN1 = SELG(9, 11);
        #undef SELG

        float R0 = sigm(bf2f(xr0) + pR0);
        float Z0 = sigm(bf2f(xz0) + pZ0);
        float N0 = tanhfast(bf2f(xn0) + R0 * (pN0 + bN0));
        h0 = N0 + Z0 * (h0 - N0);
        float R1 = sigm(bf2f(xr1) + pR1);
        float Z1 = sigm(bf2f(xz1) + pZ1);
        float N1 = tanhfast(bf2f(xn1) + R1 * (pN1 + bN1));
        h1 = N1 + Z1 * (h1 - N1);
        uint16_t hb0 = f2bf(h0), hb1 = f2bf(h1);
        *(uint16_t*)(Abuf[p ^ 1] + wr0) = hb0;
        *(uint16_t*)(Abuf[p ^ 1] + wr1) = hb1;

        if (t + 1 < L) {
            const uint16_t* src = XG + ((long)(t + 1) * 512 + rowl) * 768;
            xr0 = src[col0]; xz0 = src[256 + col0]; xn0 = src[512 + col0];
            xr1 = src[col1]; xz1 = src[256 + col1]; xn1 = src[512 + col1];
        }
        if (wy) {
            uint16_t* yd = Y + ((long)t * 512 + rowl) * 256;
            yd[col0] = hb0; yd[col1] = hb1;
        }
        bar_lds();
    }
    if (hlast) {
        hlast[rowl * 256 + col0] = h0;
        hlast[rowl * 256 + col1] = h1;
    }
}

// ---------------------------------------------------------------------------
// Kernel 3b: persistent GRU, 8-wave variant (decoder layers; r13 structure,
// bhh r/z now folded into XG upstream — only bN added here).
// ---------------------------------------------------------------------------
__global__ __launch_bounds__(512) void k_gru(
    const uint16_t* __restrict__ XG, const float* __restrict__ Whh,
    const float* __restrict__ bhh, uint16_t* __restrict__ Y,
    float* __restrict__ hlast)
{
    constexpr int L = 128;
    __shared__ __align__(16) char Abuf[2][2 * 512];
    __shared__ __align__(16) char Wt[768 * 72 + 8];
    const int tid = threadIdx.x;
    const int w = tid >> 6, l = tid & 63, lr = l & 15, lg = l >> 4;
    const int rowg0 = blockIdx.x * 2;

    ((uint32_t*)Abuf)[tid] = 0;

    #pragma unroll
    for (int it = 0; it < 6; ++it) {
        int c = it * 512 + tid; int r = c >> 2, cc = c & 3;
        bf16x8 v = cvt8(Whh + (long)r * 256 + 224 + cc * 8);
        *(int4v*)(Wt + r * 72 + cc * 16) = asint4(v);
    }

    int gb[6];
    #pragma unroll
    for (int tl = 0; tl < 6; ++tl) gb[tl] = (tl >> 1) * 256 + w * 32 + (tl & 1) * 16;
    bf16x8 wf[6][7];
    #pragma unroll
    for (int tl = 0; tl < 6; ++tl)
        #pragma unroll
        for (int ks = 0; ks < 7; ++ks)
            wf[tl][ks] = cvt8(Whh + (long)(gb[tl] + lr) * 256 + ks * 32 + lg * 8);

    const int i_  = lg & 1;
    const int sub = (lg >> 1) & 1;
    const int col = w * 32 + sub * 16 + lr;
    const float bN = bhh[512 + col];
    const long rowl = rowg0 + i_;
    const int wrbyte = i_ * 512 + ((((col * 2) & ~15) ^ (i_ << 6)) | ((col * 2) & 15));

    uint16_t xga0 = XG[rowl * 768 + col];
    uint16_t xga1 = XG[rowl * 768 + 256 + col];
    uint16_t xga2 = XG[rowl * 768 + 512 + col];
    float h = 0.f;
    const bool wy = (Y != nullptr);
    const int arow = lr & 1;
    __syncthreads();

    for (int t = 0; t < L; ++t) {
        const int p = t & 1;
        f32x4 acc[6];
        #pragma unroll
        for (int i = 0; i < 6; ++i) acc[i] = (f32x4){0.f, 0.f, 0.f, 0.f};

        const char* ab = Abuf[p];
        bf16x8 aq[4];
        #pragma unroll
        for (int i = 0; i < 4; ++i)
            aq[i] = *(bf16x8*)(ab + arow * 512 + ((i * 64 + lg * 16) ^ (arow << 6)));
        #pragma unroll
        for (int ks = 0; ks < 8; ++ks) {
            bf16x8 acur = aq[ks & 3];
            if (ks + 4 < 8)
                aq[ks & 3] = *(bf16x8*)(ab + arow * 512 + (((ks + 4) * 64 + lg * 16) ^ (arow << 6)));
            if (ks < 7) {
                #pragma unroll
                for (int tl = 0; tl < 6; ++tl) acc[tl] = mfma16(acur, wf[tl][ks], acc[tl]);
            } else {
                #pragma unroll
                for (int tl = 0; tl < 6; ++tl) {
                    bf16x8 b = *(bf16x8*)(Wt + (gb[tl] + lr) * 72 + lg * 16);
                    acc[tl] = mfma16(acur, b, acc[tl]);
                }
            }
        }

        float pre0, pre1, pre2;
        {
            float a0 = i_ ? acc[0][1] : acc[0][0];
            float a1 = i_ ? acc[1][1] : acc[1][0];
            pre0 = sub ? a1 : a0;
            float b0 = i_ ? acc[2][1] : acc[2][0];
            float b1 = i_ ? acc[3][1] : acc[3][0];
            pre1 = sub ? b1 : b0;
            float c0 = i_ ? acc[4][1] : acc[4][0];
            float c1 = i_ ? acc[5][1] : acc[5][0];
            pre2 = sub ? c1 : c0;
        }
        float xr = bf2f(xga0), xz = bf2f(xga1), xn = bf2f(xga2);
        float R = sigm(xr + pre0);
        float Z = sigm(xz + pre1);
        float N = tanhfast(xn + R * (pre2 + bN));
        h = N + Z * (h - N);
        uint16_t hb = f2bf(h);
        *(uint16_t*)(Abuf[p ^ 1] + wrbyte) = hb;

        if (t + 1 < L) {
            const uint16_t* src = XG + ((long)(t + 1) * 512 + rowl) * 768;
            xga0 = src[col]; xga1 = src[256 + col]; xga2 = src[512 + col];
        }
        if (wy) Y[((long)t * 512 + rowl) * 256 + col] = hb;
        bar_lds();
    }
    if (hlast) hlast[rowl * 256 + col] = h;
}

// ---------------------------------------------------------------------------
// Kernel 4: mu / log_var / z.
// ---------------------------------------------------------------------------
__global__ __launch_bounds__(256) void k_z(
    const float* __restrict__ hlast, const float* __restrict__ muW,
    const float* __restrict__ mub, const float* __restrict__ lvW,
    const float* __restrict__ lvb, const float* __restrict__ eps,
    float* __restrict__ mu_out, float* __restrict__ lv_out,
    float* __restrict__ zout)
{
    __shared__ float hrow[2][256];
    __shared__ float res[2][128];
    const int tid = threadIdx.x;
    const long row0 = (long)blockIdx.x * 2;
    for (int i = tid; i < 512; i += 256) ((float*)hrow)[i] = hlast[row0 * 256 + i];
    __syncthreads();
    const int lrr = tid >> 7, c = tid & 127;
    const float* Wr = (c < 64 ? muW : lvW) + (long)(c & 63) * 256;
    float acc = (c < 64) ? mub[c] : lvb[c & 63];
    const float* hr = hrow[lrr];
    #pragma unroll 8
    for (int k = 0; k < 256; k += 4) {
        f32x4 wv = *(const f32x4*)(Wr + k);
        #pragma unroll
        for (int e = 0; e < 4; ++e) acc += hr[k + e] * wv[e];
    }
    res[lrr][c] = acc;
    long row = row0 + lrr;
    if (c < 64) mu_out[row * 64 + c] = acc;
    else        lv_out[row * 64 + (c & 63)] = acc;
    __syncthreads();
    if (c < 64) {
        float m = res[lrr][c], lv = res[lrr][64 + c];
        zout[row * 64 + c] = m + eps[row * 64 + c] * __expf(0.5f * lv);
    }
}

// ---------------------------------------------------------------------------
// Kernel 5: post proj + ReLU + LN, then output proj + tanh -> x_hat (f32).
// ---------------------------------------------------------------------------
__global__ __launch_bounds__(256) void k_post(
    const uint16_t* __restrict__ D1, const float* __restrict__ pW,
    const float* __restrict__ pb, const float* __restrict__ pg,
    const float* __restrict__ pbeta, const float* __restrict__ oW,
    const float* __restrict__ ob, float* __restrict__ xhat)
{
    __shared__ __align__(16) char Bs[256 * 512];
    const int tid = threadIdx.x;
    const long rowbase = (long)blockIdx.x * 64;
    #pragma unroll
    for (int it = 0; it < 32; ++it) {
        int c = it * 256 + tid; int r = c >> 5, cc = c & 31;
        bf16x8 v = cvt8(pW + r * 256 + cc * 8);
        *(int4v*)(Bs + r * 512 + ((cc * 16) ^ ((r & 7) << 4))) = asint4(v);
    }
    __syncthreads();
    const int w = tid >> 6, l = tid & 63, lr = l & 15, lg = l >> 4;
    const long arow = rowbase + w * 16 + lr;
    bf16x8 af[8];
    #pragma unroll
    for (int ks = 0; ks < 8; ++ks) af[ks] = *(const bf16x8*)(D1 + arow * 256 + ks * 32 + lg * 8);
    f32x4 acc[16];
    #pragma unroll
    for (int i = 0; i < 16; ++i) acc[i] = (f32x4){0.f, 0.f, 0.f, 0.f};
    #pragma unroll
    for (int ks = 0; ks < 8; ++ks) {
        #pragma unroll
        for (int tl = 0; tl < 16; ++tl) {
            int n = tl * 16 + lr;
            bf16x8 b = *(bf16x8*)(Bs + n * 512 + ((ks * 64 + lg * 16) ^ ((n & 7) << 4)));
            acc[tl] = mfma16(af[ks], b, acc[tl]);
        }
    }
    float gv[16], bv[16], biasv[16];
    #pragma unroll
    for (int tl = 0; tl < 16; ++tl) {
        int col = tl * 16 + lr;
        gv[tl] = pg[col]; bv[tl] = pbeta[col]; biasv[tl] = pb[col];
    }
    uint16_t dl[16][4];
    #pragma unroll
    for (int i = 0; i < 4; ++i) {
        float s = 0.f, sq = 0.f, v[16];
        #pragma unroll
        for (int tl = 0; tl < 16; ++tl) {
            float xv = acc[tl][i] + biasv[tl]; xv = fmaxf(xv, 0.f);
            v[tl] = xv; s += xv; sq += xv * xv;
        }
        #pragma unroll
        for (int d = 1; d < 16; d <<= 1) { s += __shfl_xor(s, d); sq += __shfl_xor(sq, d); }
        float mean = s * (1.f / 256.f);
        float var  = sq * (1.f / 256.f) - mean * mean;
        float sc   = rsqrtf(var + 1e-5f);
        #pragma unroll
        for (int tl = 0; tl < 16; ++tl)
            dl[tl][i] = f2bf((v[tl] - mean) * sc * gv[tl] + bv[tl]);
    }
    __syncthreads();
    #pragma unroll
    for (int tl = 0; tl < 16; ++tl) {
        int col = tl * 16 + lr;
        #pragma unroll
        for (int i = 0; i < 4; ++i) {
            int row = w * 16 + lg * 4 + i;
            *(uint16_t*)(Bs + row * 512 + (((col * 2) & ~15) ^ ((row & 7) << 4)) + ((col * 2) & 15)) = dl[tl][i];
        }
    }
    __syncthreads();
    const int ar2 = w * 16 + lr;
    f32x4 acc2[4];
    #pragma unroll
    for (int i = 0; i < 4; ++i) acc2[i] = (f32x4){0.f, 0.f, 0.f, 0.f};
    #pragma unroll
    for (int ks = 0; ks < 8; ++ks) {
        bf16x8 a = *(bf16x8*)(Bs + ar2 * 512 + ((ks * 64 + lg * 16) ^ ((ar2 & 7) << 4)));
        #pragma unroll
        for (int tl = 0; tl < 4; ++tl) {
            int n = tl * 16 + lr;
            bf16x8 b = cvt8(oW + n * 256 + ks * 32 + lg * 8);
            acc2[tl] = mfma16(a, b, acc2[tl]);
        }
    }
    #pragma unroll
    for (int tl = 0; tl < 4; ++tl) {
        int col = tl * 16 + lr;
        float bo = ob[col];
        #pragma unroll
        for (int i = 0; i < 4; ++i) {
            long ri = rowbase + w * 16 + lg * 4 + i;
            long b = ri & 511, t = ri >> 9;
            xhat[(b * 128 + t) * 64 + col] = tanhfast(acc2[tl][i] + bo);
        }
    }
}

// ---------------------------------------------------------------------------
extern "C" void kernel_launch(void* const* d_in, const int* in_sizes, int n_in,
                              void* d_out, int out_size, void* d_ws, size_t ws_size,
                              hipStream_t stream)
{
    (void)in_sizes; (void)n_in; (void)out_size; (void)ws_size;
    const float* x     = (const float*)d_in[0];
    const float* eps   = (const float*)d_in[1];
    const float* dnz   = (const float*)d_in[2];
    const float* in_W  = (const float*)d_in[3];
    const float* in_b  = (const float*)d_in[4];
    const float* in_g  = (const float*)d_in[5];
    const float* in_be = (const float*)d_in[6];
    const float* eW0i  = (const float*)d_in[7];
    const float* eW0h  = (const float*)d_in[8];
    const float* eb0i  = (const float*)d_in[9];
    const float* eb0h  = (const float*)d_in[10];
    const float* eW1i  = (const float*)d_in[11];
    const float* eW1h  = (const float*)d_in[12];
    const float* eb1i  = (const float*)d_in[13];
    const float* eb1h  = (const float*)d_in[14];
    const float* mu_W  = (const float*)d_in[15];
    const float* mu_b  = (const float*)d_in[16];
    const float* lv_W  = (const float*)d_in[17];
    const float* lv_b  = (const float*)d_in[18];
    const float* dW0i  = (const float*)d_in[19];
    const float* dW0h  = (const float*)d_in[20];
    const float* db0i  = (const float*)d_in[21];
    const float* db0h  = (const float*)d_in[22];
    const float* dW1i  = (const float*)d_in[23];
    const float* dW1h  = (const float*)d_in[24];
    const float* db1i  = (const float*)d_in[25];
    const float* db1h  = (const float*)d_in[26];
    const float* postW = (const float*)d_in[27];
    const float* postb = (const float*)d_in[28];
    const float* postg = (const float*)d_in[29];
    const float* postbe= (const float*)d_in[30];
    const float* outW  = (const float*)d_in[31];
    const float* outb  = (const float*)d_in[32];

    char* ws = (char*)d_ws;
    uint16_t* XG   = (uint16_t*)(ws);                 // 100663296 B
    uint16_t* YA   = (uint16_t*)(ws + 100663296);     // 33554432 B
    uint16_t* YB   = (uint16_t*)(ws + 134217728);     // 33554432 B
    float*    hlast= (float*)   (ws + 167772160);     // 524288 B
    float*    zbuf = (float*)   (ws + 168296448);     // 131072 B

    float* out    = (float*)d_out;
    float* mu_out = out + 4194304;
    float* lv_out = out + 4194304 + 32768;

    dim3 b256(256), b512(512);
    dim3 gxg(64, 4);

    k_inproj<<<1024, b256, 0, stream>>>(x, in_W, in_b, in_g, in_be, YA);
    k_xg<256,false><<<gxg, b512, 0, stream>>>(YA, eW0i, eb0i, eb0h, XG, nullptr, nullptr);
    k_gru4<<<256, b256, 0, stream>>>(XG, eW0h, eb0h, YB, nullptr);          // A: 4-wave
    k_xg<256,false><<<gxg, b512, 0, stream>>>(YB, eW1i, eb1i, eb1h, XG, nullptr, nullptr);
    k_gru4<<<256, b256, 0, stream>>>(XG, eW1h, eb1h, nullptr, hlast);       // A: 4-wave
    k_z<<<256, b256, 0, stream>>>(hlast, mu_W, mu_b, lv_W, lv_b, eps, mu_out, lv_out, zbuf);
    k_xg<64,true><<<gxg, b512, 0, stream>>>(nullptr, dW0i, db0i, db0h, XG, zbuf, dnz);
    k_gru<<<256, b512, 0, stream>>>(XG, dW0h, db0h, YA, nullptr);           // B: 8-wave
    k_xg<256,false><<<gxg, b512, 0, stream>>>(YA, dW1i, db1i, db1h, XG, nullptr, nullptr);
    k_gru<<<256, b512, 0, stream>>>(XG, dW1h, db1h, YB, nullptr);           // B: 8-wave
    k_post<<<1024, b256, 0, stream>>>(YB, postW, postb, postg, postbe, outW, outb, out);
}

// Round 15
// 954.951 us; speedup vs baseline: 1.1854x; 1.1854x over previous
//
#include <hip/hip_runtime.h>
#include <hip/hip_bf16.h>
#include <stdint.h>

#define DEVI static __device__ __forceinline__

typedef __bf16 bf16x8 __attribute__((ext_vector_type(8)));
typedef float f32x4 __attribute__((ext_vector_type(4)));
typedef int   int4v __attribute__((ext_vector_type(4)));
typedef int   int2v __attribute__((ext_vector_type(2)));

DEVI float bf2f(uint16_t u){ uint32_t x = ((uint32_t)u) << 16; float f; __builtin_memcpy(&f, &x, 4); return f; }
DEVI uint16_t f2bf(float f){ uint32_t u; __builtin_memcpy(&u, &f, 4); uint32_t r = (u + 0x7FFFu + ((u >> 16) & 1u)) >> 16; return (uint16_t)r; }
DEVI float frcp(float x){ return __builtin_amdgcn_rcpf(x); }
DEVI float sigm(float x){ return frcp(1.f + __expf(-x)); }
DEVI float tanhfast(float x){ return 1.f - 2.f * frcp(1.f + __expf(2.f * x)); }
DEVI f32x4 mfma16(bf16x8 a, bf16x8 b, f32x4 c){ return __builtin_amdgcn_mfma_f32_16x16x32_bf16(a, b, c, 0, 0, 0); }

DEVI bf16x8 cvt8(const float* __restrict__ p){
    f32x4 a = *(const f32x4*)p, b = *(const f32x4*)(p + 4);
    union { bf16x8 v; uint16_t u[8]; } r;
    #pragma unroll
    for (int e = 0; e < 4; ++e) { r.u[e] = f2bf(a[e]); r.u[4 + e] = f2bf(b[e]); }
    return r.v;
}
DEVI int4v asint4(bf16x8 v){ int4v r; __builtin_memcpy(&r, &v, 16); return r; }

// raw barrier: lgkm drain only (vm ops — prefetch loads / Y stores — stay in flight)
DEVI void bar_lds(){
    asm volatile("s_waitcnt lgkmcnt(0)" ::: "memory");
    __builtin_amdgcn_s_barrier();
    __builtin_amdgcn_sched_barrier(0);
}

// XG layout (row-major, t-major rows): element (t, b, c) at (t*512 + b)*768 + c.
// XG cols 0..511 (r,z gates) carry bhh folded in; cols 512..767 (n gate) do not.

// ---------------------------------------------------------------------------
// Kernel 1: input projection (B*L,64)@(64,256) + bias + ReLU + LN -> Y bf16
// ---------------------------------------------------------------------------
__global__ __launch_bounds__(256) void k_inproj(
    const float* __restrict__ X, const float* __restrict__ W,
    const float* __restrict__ bias, const float* __restrict__ g,
    const float* __restrict__ beta, uint16_t* __restrict__ Y)
{
    __shared__ __align__(16) char As[64 * 128];
    __shared__ __align__(16) char Bs[256 * 128];
    __shared__ __align__(16) char Cs[64 * 520];
    const int tid = threadIdx.x;
    const long rowbase = (long)blockIdx.x * 64;

    #pragma unroll
    for (int it = 0; it < 2; ++it) {
        int c = it * 256 + tid; int r = c >> 3, cc = c & 7;
        bf16x8 v = cvt8(X + (rowbase + r) * 64 + cc * 8);
        *(int4v*)(As + r * 128 + ((cc * 16) ^ ((r & 7) << 4))) = asint4(v);
    }
    #pragma unroll
    for (int it = 0; it < 8; ++it) {
        int c = it * 256 + tid; int r = c >> 3, cc = c & 7;
        bf16x8 v = cvt8(W + r * 64 + cc * 8);
        *(int4v*)(Bs + r * 128 + ((cc * 16) ^ ((r & 7) << 4))) = asint4(v);
    }
    __syncthreads();

    const int w = tid >> 6, l = tid & 63, lr = l & 15, lg = l >> 4;
    f32x4 acc[16];
    #pragma unroll
    for (int i = 0; i < 16; ++i) acc[i] = (f32x4){0.f, 0.f, 0.f, 0.f};
    const int arow = w * 16 + lr;
    #pragma unroll
    for (int ks = 0; ks < 2; ++ks) {
        bf16x8 a = *(bf16x8*)(As + arow * 128 + ((ks * 64 + lg * 16) ^ ((arow & 7) << 4)));
        #pragma unroll
        for (int tl = 0; tl < 16; ++tl) {
            int n = tl * 16 + lr;
            bf16x8 b = *(bf16x8*)(Bs + n * 128 + ((ks * 64 + lg * 16) ^ ((n & 7) << 4)));
            acc[tl] = mfma16(a, b, acc[tl]);
        }
    }
    float gv[16], bv[16], biasv[16];
    #pragma unroll
    for (int tl = 0; tl < 16; ++tl) {
        int col = tl * 16 + lr;
        gv[tl] = g[col]; bv[tl] = beta[col]; biasv[tl] = bias[col];
    }
    #pragma unroll
    for (int i = 0; i < 4; ++i) {
        float s = 0.f, sq = 0.f, v[16];
        #pragma unroll
        for (int tl = 0; tl < 16; ++tl) {
            float xv = acc[tl][i] + biasv[tl]; xv = fmaxf(xv, 0.f);
            v[tl] = xv; s += xv; sq += xv * xv;
        }
        #pragma unroll
        for (int d = 1; d < 16; d <<= 1) { s += __shfl_xor(s, d); sq += __shfl_xor(sq, d); }
        float mean = s * (1.f / 256.f);
        float var  = sq * (1.f / 256.f) - mean * mean;
        float sc   = rsqrtf(var + 1e-5f);
        int rl = w * 16 + lg * 4 + i;
        #pragma unroll
        for (int tl = 0; tl < 16; ++tl)
            *(uint16_t*)(Cs + rl * 520 + (tl * 16 + lr) * 2) =
                f2bf((v[tl] - mean) * sc * gv[tl] + bv[tl]);
    }
    __syncthreads();
    #pragma unroll
    for (int it = 0; it < 16; ++it) {
        int idx = it * 256 + tid;
        int rl = idx >> 6, ch = idx & 63;
        long rg = rowbase + rl;
        long ri = ((rg & 127) << 9) + (rg >> 7);      // t-major
        *(int2v*)(Y + ri * 256 + ch * 4) = *(int2v*)(Cs + rl * 520 + ch * 8);
    }
}

// ---------------------------------------------------------------------------
// Kernel 2: input-gate GEMM. bhh folded into bias for cols < 512 (r,z gates).
// LDS-staged coalesced XG stores. grid (64, 4) x 512 thr.
// ---------------------------------------------------------------------------
template<int KIN, bool ZBUILD>
__global__ __launch_bounds__(512) void k_xg(
    const uint16_t* __restrict__ A, const float* __restrict__ W,
    const float* __restrict__ bias, const float* __restrict__ bhh,
    uint16_t* __restrict__ XG,
    const float* __restrict__ zbuf, const float* __restrict__ noise)
{
    constexpr int KB = KIN * 2;
    constexpr int KS = KIN / 32;
    __shared__ __align__(16) char Bs[192 * KB];
    __shared__ __align__(16) char Cs[128 * 400];
    const int tid = threadIdx.x;
    const int nb = blockIdx.y;

    constexpr int CPR = KIN / 8;
    for (int c = tid; c < 192 * CPR; c += 512) {
        int r = c / CPR, cc = c % CPR;
        bf16x8 v = cvt8(W + (long)(nb * 192 + r) * KIN + cc * 8);
        *(int4v*)(Bs + r * KB + ((cc * 16) ^ ((r & 7) << 4))) = asint4(v);
    }
    __syncthreads();

    const int w = tid >> 6, l = tid & 63, lr = l & 15, lg = l >> 4;
    float bvs[12];
    #pragma unroll
    for (int tl = 0; tl < 12; ++tl) {
        int colg = nb * 192 + tl * 16 + lr;
        bvs[tl] = bias[colg] + (colg < 512 ? bhh[colg] : 0.f);
    }

    for (int rt = 0; rt < 8; ++rt) {
        const long rowb = (long)blockIdx.x * 1024 + rt * 128;
        const long ria  = rowb + w * 16 + lr;
        bf16x8 a[KS];
        if constexpr (!ZBUILD) {
            #pragma unroll
            for (int ks = 0; ks < KS; ++ks)
                a[ks] = *(const bf16x8*)(A + ria * KIN + ks * 32 + lg * 8);
        } else {
            int b = (int)(ria & 511), t = (int)(ria >> 9);
            #pragma unroll
            for (int ks = 0; ks < KS; ++ks) {
                int k0 = ks * 32 + lg * 8;
                const float* zr = zbuf + b * 64 + k0;
                const float* nr = noise + ((long)b * 128 + t) * 64 + k0;
                f32x4 z0 = *(const f32x4*)zr, z1 = *(const f32x4*)(zr + 4);
                f32x4 n0 = *(const f32x4*)nr, n1 = *(const f32x4*)(nr + 4);
                union { bf16x8 v; uint16_t u[8]; } un;
                #pragma unroll
                for (int e = 0; e < 4; ++e) {
                    un.u[e]     = f2bf(z0[e] + 0.05f * n0[e]);
                    un.u[4 + e] = f2bf(z1[e] + 0.05f * n1[e]);
                }
                a[ks] = un.v;
            }
        }
        f32x4 acc[12];
        #pragma unroll
        for (int i = 0; i < 12; ++i) acc[i] = (f32x4){0.f, 0.f, 0.f, 0.f};
        #pragma unroll
        for (int ks = 0; ks < KS; ++ks) {
            #pragma unroll
            for (int tl = 0; tl < 12; ++tl) {
                int n = tl * 16 + lr;
                bf16x8 b = *(bf16x8*)(Bs + n * KB + ((ks * 64 + lg * 16) ^ ((n & 7) << 4)));
                acc[tl] = mfma16(a[ks], b, acc[tl]);
            }
        }
        #pragma unroll
        for (int tl = 0; tl < 12; ++tl) {
            #pragma unroll
            for (int i = 0; i < 4; ++i)
                *(uint16_t*)(Cs + (w * 16 + lg * 4 + i) * 400 + (tl * 16 + lr) * 2) =
                    f2bf(acc[tl][i] + bvs[tl]);
        }
        __syncthreads();
        #pragma unroll
        for (int it = 0; it < 6; ++it) {
            int idx = it * 512 + tid;
            int row = idx / 24, ch = idx % 24;
            *(int4v*)(XG + (rowb + row) * 768 + nb * 192 + ch * 8) =
                *(int4v*)(Cs + row * 400 + ch * 16);
        }
        __syncthreads();
    }
}

// ---------------------------------------------------------------------------
// Kernel 3: persistent GRU (best-known r13 structure). 256 blocks x 512 thr,
// 2 rows/block. Whh k[0,224) in VGPRs (wf[6][7]=168, no spill); k[224,256)
// in LDS at 72B stride (conflict-free). h as 2x512B, disjoint-bank swizzle.
// 4-deep circular A prefetch. No setprio. One lgkm barrier per step except
// the (dead) last. bhh r/z folded into XG upstream; bN applied here.
// ---------------------------------------------------------------------------
__global__ __launch_bounds__(512) void k_gru(
    const uint16_t* __restrict__ XG, const float* __restrict__ Whh,
    const float* __restrict__ bhh, uint16_t* __restrict__ Y,
    float* __restrict__ hlast)
{
    constexpr int L = 128;
    __shared__ __align__(16) char Abuf[2][2 * 512];
    __shared__ __align__(16) char Wt[768 * 72 + 8];
    const int tid = threadIdx.x;
    const int w = tid >> 6, l = tid & 63, lr = l & 15, lg = l >> 4;
    const int rowg0 = blockIdx.x * 2;

    ((uint32_t*)Abuf)[tid] = 0;

    #pragma unroll
    for (int it = 0; it < 6; ++it) {
        int c = it * 512 + tid; int r = c >> 2, cc = c & 3;
        bf16x8 v = cvt8(Whh + (long)r * 256 + 224 + cc * 8);
        *(int4v*)(Wt + r * 72 + cc * 16) = asint4(v);
    }

    int gb[6];
    #pragma unroll
    for (int tl = 0; tl < 6; ++tl) gb[tl] = (tl >> 1) * 256 + w * 32 + (tl & 1) * 16;
    bf16x8 wf[6][7];
    #pragma unroll
    for (int tl = 0; tl < 6; ++tl)
        #pragma unroll
        for (int ks = 0; ks < 7; ++ks)
            wf[tl][ks] = cvt8(Whh + (long)(gb[tl] + lr) * 256 + ks * 32 + lg * 8);

    const int i_  = lg & 1;
    const int sub = (lg >> 1) & 1;
    const int col = w * 32 + sub * 16 + lr;
    const float bN = bhh[512 + col];
    const long rowl = rowg0 + i_;
    const int wrbyte = i_ * 512 + ((((col * 2) & ~15) ^ (i_ << 6)) | ((col * 2) & 15));

    uint16_t xga0 = XG[rowl * 768 + col];
    uint16_t xga1 = XG[rowl * 768 + 256 + col];
    uint16_t xga2 = XG[rowl * 768 + 512 + col];
    float h = 0.f;
    const bool wy = (Y != nullptr);
    const int arow = lr & 1;
    const f32x4 zero4 = (f32x4){0.f, 0.f, 0.f, 0.f};
    __syncthreads();

    for (int t = 0; t < L; ++t) {
        const int p = t & 1;
        f32x4 acc[6];
        #pragma unroll
        for (int i = 0; i < 6; ++i) acc[i] = zero4;

        const char* ab = Abuf[p];
        bf16x8 aq[4];
        #pragma unroll
        for (int i = 0; i < 4; ++i)
            aq[i] = *(bf16x8*)(ab + arow * 512 + ((i * 64 + lg * 16) ^ (arow << 6)));
        #pragma unroll
        for (int ks = 0; ks < 8; ++ks) {
            bf16x8 acur = aq[ks & 3];
            if (ks + 4 < 8)
                aq[ks & 3] = *(bf16x8*)(ab + arow * 512 + (((ks + 4) * 64 + lg * 16) ^ (arow << 6)));
            if (ks < 7) {
                #pragma unroll
                for (int tl = 0; tl < 6; ++tl) acc[tl] = mfma16(acur, wf[tl][ks], acc[tl]);
            } else {
                #pragma unroll
                for (int tl = 0; tl < 6; ++tl) {
                    bf16x8 b = *(bf16x8*)(Wt + (gb[tl] + lr) * 72 + lg * 16);
                    acc[tl] = mfma16(acur, b, acc[tl]);
                }
            }
        }

        float pre0, pre1, pre2;
        {
            float a0 = i_ ? acc[0][1] : acc[0][0];
            float a1 = i_ ? acc[1][1] : acc[1][0];
            pre0 = sub ? a1 : a0;
            float b0 = i_ ? acc[2][1] : acc[2][0];
            float b1 = i_ ? acc[3][1] : acc[3][0];
            pre1 = sub ? b1 : b0;
            float c0 = i_ ? acc[4][1] : acc[4][0];
            float c1 = i_ ? acc[5][1] : acc[5][0];
            pre2 = sub ? c1 : c0;
        }
        float xr = bf2f(xga0), xz = bf2f(xga1), xn = bf2f(xga2);
        float R = sigm(xr + pre0);
        float Z = sigm(xz + pre1);
        float N = tanhfast(xn + R * (pre2 + bN));
        h = N + Z * (h - N);
        uint16_t hb = f2bf(h);
        *(uint16_t*)(Abuf[p ^ 1] + wrbyte) = hb;

        if (t + 1 < L) {
            const uint16_t* src = XG + ((long)(t + 1) * 512 + rowl) * 768;
            xga0 = src[col]; xga1 = src[256 + col]; xga2 = src[512 + col];
        }
        if (wy) Y[((long)t * 512 + rowl) * 256 + col] = hb;
        if (t + 1 < L) bar_lds();              // final-iteration barrier is dead
    }
    if (hlast) hlast[rowl * 256 + col] = h;
}

// ---------------------------------------------------------------------------
// Kernel 4: mu / log_var / z.
// ---------------------------------------------------------------------------
__global__ __launch_bounds__(256) void k_z(
    const float* __restrict__ hlast, const float* __restrict__ muW,
    const float* __restrict__ mub, const float* __restrict__ lvW,
    const float* __restrict__ lvb, const float* __restrict__ eps,
    float* __restrict__ mu_out, float* __restrict__ lv_out,
    float* __restrict__ zout)
{
    __shared__ float hrow[2][256];
    __shared__ float res[2][128];
    const int tid = threadIdx.x;
    const long row0 = (long)blockIdx.x * 2;
    for (int i = tid; i < 512; i += 256) ((float*)hrow)[i] = hlast[row0 * 256 + i];
    __syncthreads();
    const int lrr = tid >> 7, c = tid & 127;
    const float* Wr = (c < 64 ? muW : lvW) + (long)(c & 63) * 256;
    float acc = (c < 64) ? mub[c] : lvb[c & 63];
    const float* hr = hrow[lrr];
    #pragma unroll 8
    for (int k = 0; k < 256; k += 4) {
        f32x4 wv = *(const f32x4*)(Wr + k);
        #pragma unroll
        for (int e = 0; e < 4; ++e) acc += hr[k + e] * wv[e];
    }
    res[lrr][c] = acc;
    long row = row0 + lrr;
    if (c < 64) mu_out[row * 64 + c] = acc;
    else        lv_out[row * 64 + (c & 63)] = acc;
    __syncthreads();
    if (c < 64) {
        float m = res[lrr][c], lv = res[lrr][64 + c];
        zout[row * 64 + c] = m + eps[row * 64 + c] * __expf(0.5f * lv);
    }
}

// ---------------------------------------------------------------------------
// Kernel 5: post proj + ReLU + LN, then output proj + tanh -> x_hat (f32).
// ---------------------------------------------------------------------------
__global__ __launch_bounds__(256) void k_post(
    const uint16_t* __restrict__ D1, const float* __restrict__ pW,
    const float* __restrict__ pb, const float* __restrict__ pg,
    const float* __restrict__ pbeta, const float* __restrict__ oW,
    const float* __restrict__ ob, float* __restrict__ xhat)
{
    __shared__ __align__(16) char Bs[256 * 512];
    const int tid = threadIdx.x;
    const long rowbase = (long)blockIdx.x * 64;
    #pragma unroll
    for (int it = 0; it < 32; ++it) {
        int c = it * 256 + tid; int r = c >> 5, cc = c & 31;
        bf16x8 v = cvt8(pW + r * 256 + cc * 8);
        *(int4v*)(Bs + r * 512 + ((cc * 16) ^ ((r & 7) << 4))) = asint4(v);
    }
    __syncthreads();
    const int w = tid >> 6, l = tid & 63, lr = l & 15, lg = l >> 4;
    const long arow = rowbase + w * 16 + lr;
    bf16x8 af[8];
    #pragma unroll
    for (int ks = 0; ks < 8; ++ks) af[ks] = *(const bf16x8*)(D1 + arow * 256 + ks * 32 + lg * 8);
    f32x4 acc[16];
    #pragma unroll
    for (int i = 0; i < 16; ++i) acc[i] = (f32x4){0.f, 0.f, 0.f, 0.f};
    #pragma unroll
    for (int ks = 0; ks < 8; ++ks) {
        #pragma unroll
        for (int tl = 0; tl < 16; ++tl) {
            int n = tl * 16 + lr;
            bf16x8 b = *(bf16x8*)(Bs + n * 512 + ((ks * 64 + lg * 16) ^ ((n & 7) << 4)));
            acc[tl] = mfma16(af[ks], b, acc[tl]);
        }
    }
    float gv[16], bv[16], biasv[16];
    #pragma unroll
    for (int tl = 0; tl < 16; ++tl) {
        int col = tl * 16 + lr;
        gv[tl] = pg[col]; bv[tl] = pbeta[col]; biasv[tl] = pb[col];
    }
    uint16_t dl[16][4];
    #pragma unroll
    for (int i = 0; i < 4; ++i) {
        float s = 0.f, sq = 0.f, v[16];
        #pragma unroll
        for (int tl = 0; tl < 16; ++tl) {
            float xv = acc[tl][i] + biasv[tl]; xv = fmaxf(xv, 0.f);
            v[tl] = xv; s += xv; sq += xv * xv;
        }
        #pragma unroll
        for (int d = 1; d < 16; d <<= 1) { s += __shfl_xor(s, d); sq += __shfl_xor(sq, d); }
        float mean = s * (1.f / 256.f);
        float var  = sq * (1.f / 256.f) - mean * mean;
        float sc   = rsqrtf(var + 1e-5f);
        #pragma unroll
        for (int tl = 0; tl < 16; ++tl)
            dl[tl][i] = f2bf((v[tl] - mean) * sc * gv[tl] + bv[tl]);
    }
    __syncthreads();
    #pragma unroll
    for (int tl = 0; tl < 16; ++tl) {
        int col = tl * 16 + lr;
        #pragma unroll
        for (int i = 0; i < 4; ++i) {
            int row = w * 16 + lg * 4 + i;
            *(uint16_t*)(Bs + row * 512 + (((col * 2) & ~15) ^ ((row & 7) << 4)) + ((col * 2) & 15)) = dl[tl][i];
        }
    }
    __syncthreads();
    const int ar2 = w * 16 + lr;
    f32x4 acc2[4];
    #pragma unroll
    for (int i = 0; i < 4; ++i) acc2[i] = (f32x4){0.f, 0.f, 0.f, 0.f};
    #pragma unroll
    for (int ks = 0; ks < 8; ++ks) {
        bf16x8 a = *(bf16x8*)(Bs + ar2 * 512 + ((ks * 64 + lg * 16) ^ ((ar2 & 7) << 4)));
        #pragma unroll
        for (int tl = 0; tl < 4; ++tl) {
            int n = tl * 16 + lr;
            bf16x8 b = cvt8(oW + n * 256 + ks * 32 + lg * 8);
            acc2[tl] = mfma16(a, b, acc2[tl]);
        }
    }
    #pragma unroll
    for (int tl = 0; tl < 4; ++tl) {
        int col = tl * 16 + lr;
        float bo = ob[col];
        #pragma unroll
        for (int i = 0; i < 4; ++i) {
            long ri = rowbase + w * 16 + lg * 4 + i;
            long b = ri & 511, t = ri >> 9;
            xhat[(b * 128 + t) * 64 + col] = tanhfast(acc2[tl][i] + bo);
        }
    }
}

// ---------------------------------------------------------------------------
extern "C" void kernel_launch(void* const* d_in, const int* in_sizes, int n_in,
                              void* d_out, int out_size, void* d_ws, size_t ws_size,
                              hipStream_t stream)
{
    (void)in_sizes; (void)n_in; (void)out_size; (void)ws_size;
    const float* x     = (const float*)d_in[0];
    const float* eps   = (const float*)d_in[1];
    const float* dnz   = (const float*)d_in[2];
    const float* in_W  = (const float*)d_in[3];
    const float* in_b  = (const float*)d_in[4];
    const float* in_g  = (const float*)d_in[5];
    const float* in_be = (const float*)d_in[6];
    const float* eW0i  = (const float*)d_in[7];
    const float* eW0h  = (const float*)d_in[8];
    const float* eb0i  = (const float*)d_in[9];
    const float* eb0h  = (const float*)d_in[10];
    const float* eW1i  = (const float*)d_in[11];
    const float* eW1h  = (const float*)d_in[12];
    const float* eb1i  = (const float*)d_in[13];
    const float* eb1h  = (const float*)d_in[14];
    const float* mu_W  = (const float*)d_in[15];
    const float* mu_b  = (const float*)d_in[16];
    const float* lv_W  = (const float*)d_in[17];
    const float* lv_b  = (const float*)d_in[18];
    const float* dW0i  = (const float*)d_in[19];
    const float* dW0h  = (const float*)d_in[20];
    const float* db0i  = (const float*)d_in[21];
    const float* db0h  = (const float*)d_in[22];
    const float* dW1i  = (const float*)d_in[23];
    const float* dW1h  = (const float*)d_in[24];
    const float* db1i  = (const float*)d_in[25];
    const float* db1h  = (const float*)d_in[26];
    const float* postW = (const float*)d_in[27];
    const float* postb = (const float*)d_in[28];
    const float* postg = (const float*)d_in[29];
    const float* postbe= (const float*)d_in[30];
    const float* outW  = (const float*)d_in[31];
    const float* outb  = (const float*)d_in[32];

    char* ws = (char*)d_ws;
    uint16_t* XG   = (uint16_t*)(ws);                 // 100663296 B
    uint16_t* YA   = (uint16_t*)(ws + 100663296);     // 33554432 B
    uint16_t* YB   = (uint16_t*)(ws + 134217728);     // 33554432 B
    float*    hlast= (float*)   (ws + 167772160);     // 524288 B
    float*    zbuf = (float*)   (ws + 168296448);     // 131072 B

    float* out    = (float*)d_out;
    float* mu_out = out + 4194304;
    float* lv_out = out + 4194304 + 32768;

    dim3 b256(256), b512(512);
    dim3 gxg(64, 4);

    k_inproj<<<1024, b256, 0, stream>>>(x, in_W, in_b, in_g, in_be, YA);
    k_xg<256,false><<<gxg, b512, 0, stream>>>(YA, eW0i, eb0i, eb0h, XG, nullptr, nullptr);
    k_gru<<<256, b512, 0, stream>>>(XG, eW0h, eb0h, YB, nullptr);
    k_xg<256,false><<<gxg, b512, 0, stream>>>(YB, eW1i, eb1i, eb1h, XG, nullptr, nullptr);
    k_gru<<<256, b512, 0, stream>>>(XG, eW1h, eb1h, nullptr, hlast);
    k_z<<<256, b256, 0, stream>>>(hlast, mu_W, mu_b, lv_W, lv_b, eps, mu_out, lv_out, zbuf);
    k_xg<64,true><<<gxg, b512, 0, stream>>>(nullptr, dW0i, db0i, db0h, XG, zbuf, dnz);
    k_gru<<<256, b512, 0, stream>>>(XG, dW0h, db0h, YA, nullptr);
    k_xg<256,false><<<gxg, b512, 0, stream>>>(YA, dW1i, db1i, db1h, XG, nullptr, nullptr);
    k_gru<<<256, b512, 0, stream>>>(XG, dW1h, db1h, YB, nullptr);
    k_post<<<1024, b256, 0, stream>>>(YB, postW, postb, postg, postbe, outW, outb, out);
}